// Round 12
// baseline (270.912 us; speedup 1.0000x reference)
//
#include <hip/hip_runtime.h>
#include <math.h>

// Fused Conv3d(3->16, k=3, valid) + bias + min over D + softmax over C.
// N=16, CIN=3, COUT=16, K=3, D=H=W=64 -> out [16,16,62,62] fp32.
//
// R15: R12 structure (4 px/thread, tile 8h x 32w, grid 256, wave-per-
// channel, SGPR weights via rolled ci, double-buffered global_load_lds,
// LDS softmax exchange) + __launch_bounds__(1024, 1).
// Attribute ledger, re-derived from ALL data: amdgpu_waves_per_eu is
// IGNORED by this toolchain (R14: VGPR=64 + 172MB spill, identical to
// R12's no-attr run). The only honored knob is launch_bounds' 2nd arg
// (cap ~ 256/arg from R7/R9). Default for a 1024-thr block targets max
// occupancy -> 64-VGPR budget -> Aacc[10][4] (40 regs) spills. Arg=1
// requests loosest occupancy; the HW flat-workgroup-size bound (16 waves
// co-resident -> <=128 VGPR) then clamps the budget at 128 > ~90 need.
// Pipe model w/o spill: FMA issue ~69us/SIMD (4 waves x 20.7k x 2cyc),
// LDS ~45us/CU (b128+b64 per 36 FMAs, half of R11) -> wall ~120-150us
// vs champion R11 171us.
// Tripwires: VGPR in (64,128]? WRITE ~4.6MB? A third VGPR=64 reading
// kills this path -> CH=4-fits-64 or revert to R11.

#define CH 8  // d-slices per staged chunk

__global__ __launch_bounds__(1024, 1)
void conv3d_min_softmax(
    const float* __restrict__ x,     // [16,3,64,64,64]
    const float* __restrict__ wgt,   // [16,3,3,3,3]
    const float* __restrict__ bias,  // [16]
    float* __restrict__ out)         // [16,16,62,62]
{
    const int tid = threadIdx.x;
    // wave id == output channel; readfirstlane forces wave-uniform -> SGPR
    const int wv  = __builtin_amdgcn_readfirstlane(tid >> 6);
    const int l   = tid & 63;
    const int r0  = l >> 3;           // output row within tile (0..7)
    const int cg  = l & 7;            // col group (0..7)
    const int wc  = cg * 4;           // tile col of px0 (16B-aligned reads)
    const int n   = blockIdx.z;
    const int h0  = blockIdx.y * 8;   // 8 h-tiles cover rows 0..63 (62 valid)
    const int w0  = blockIdx.x * 32;  // 2 w-tiles cover cols 0..63 (62 valid)

    // staged x, double-buffered: [3 ci][CH dd][10 rows][36 cols] = 8640 f
    // = 2160 float4 slots (slot F <-> float index 4F, lane-linear for DMA).
    __shared__ __align__(16) float sx[2][8640];
    // softmax exchange: [256 px][17] (stride 17 -> conflict-free reads)
    __shared__ float sm[256 * 17];

    const float bv = bias[wv];

    // ---- hoisted staging address math (chunk 0) ----
    // slot F -> (ci, dd, rw, g):  F = ((ci*8+dd)*10 + rw)*9 + g
    int goff[3];  // global BYTE offsets; k=2 used only by tid<112
#pragma unroll
    for (int k = 0; k < 3; ++k) {
        int F = tid + 1024 * k;
        if (F > 2159) F = 2159;          // unused lanes: harmless dup
        int ci  = F / 720;               // 720 = 8*10*9
        int rem = F - ci * 720;
        int dd  = rem / 90;              // 90 = 10*9
        int rr  = rem - dd * 90;
        int rw  = rr / 9;
        int g   = rr - rw * 9;
        int gh  = h0 + rw;  if (gh > 63) gh = 63;   // clamp: halo, unused
        int gw  = w0 + g * 4; if (gw > 60) gw = 60; // clamp: cols>=62 unused
        goff[k] = (((ci * 64 + dd) * 64 + gh) * 64 + gw) * 4;
    }
    const char* xb = (const char*)(x + (size_t)n * 3 * 64 * 64 * 64);

    // accumulator bank: Aacc[j][px], j = d' - (c*8 - 2). j=0,1 carry
    // partials from the previous chunk; j=8,9 carry out. Static idx only.
    float Aacc[10][4];
#pragma unroll
    for (int j = 0; j < 10; ++j)
#pragma unroll
        for (int p = 0; p < 4; ++p) Aacc[j][p] = 0.f;
    float mv[4] = {1e30f, 1e30f, 1e30f, 1e30f};

    // ---- issue chunk 0 DMA (buffer 0) ----
    {
        char* lb = (char*)&sx[0][0];
        __builtin_amdgcn_global_load_lds(
            (const void*)(xb + goff[0]), (void*)(lb + tid * 16), 16, 0, 0);
        __builtin_amdgcn_global_load_lds(
            (const void*)(xb + goff[1]),
            (void*)(lb + (1024 + tid) * 16), 16, 0, 0);
        if (tid < 112)
            __builtin_amdgcn_global_load_lds(
                (const void*)(xb + goff[2]),
                (void*)(lb + (2048 + tid) * 16), 16, 0, 0);
    }

    for (int c = 0; c < 64 / CH; ++c) {
        // Drains vmcnt(0): chunk c's DMA landed; other buffer now free.
        __syncthreads();

        // ---- issue chunk c+1 DMA; flies during this chunk's compute ----
        if (c < 7) {
            const char* xc = xb + (size_t)(c + 1) * (CH * 64 * 64 * 4);
            char* lb = (char*)&sx[(c + 1) & 1][0];
            __builtin_amdgcn_global_load_lds(
                (const void*)(xc + goff[0]), (void*)(lb + tid * 16),
                16, 0, 0);
            __builtin_amdgcn_global_load_lds(
                (const void*)(xc + goff[1]),
                (void*)(lb + (1024 + tid) * 16), 16, 0, 0);
            if (tid < 112)
                __builtin_amdgcn_global_load_lds(
                    (const void*)(xc + goff[2]),
                    (void*)(lb + (2048 + tid) * 16), 16, 0, 0);
        }

        const float* S = sx[c & 1];

        // ---- compute: ci ROLLED so only 27 weights live (SGPR-resident)
#pragma unroll 1
        for (int ci = 0; ci < 3; ++ci) {
            float wsc[27];  // wave-uniform -> s_load -> SGPRs
            {
                const float* wp_ = wgt + (wv * 3 + ci) * 27;
#pragma unroll
                for (int i = 0; i < 27; ++i) wsc[i] = wp_[i];
            }
            const float* Sci = S + ci * (CH * 10 * 36) + r0 * 36 + wc;
#pragma unroll
            for (int dd = 0; dd < CH; ++dd) {
#pragma unroll
                for (int kh = 0; kh < 3; ++kh) {
                    const float4 a = *(const float4*)&Sci[(dd * 10 + kh) * 36];
                    const float2 b =
                        *(const float2*)&Sci[(dd * 10 + kh) * 36 + 4];
                    const float row[6] = {a.x, a.y, a.z, a.w, b.x, b.y};
#pragma unroll
                    for (int kw = 0; kw < 3; ++kw) {
                        const float wk0 = wsc[0  + kh * 3 + kw];  // kd=0
                        const float wk1 = wsc[9  + kh * 3 + kw];  // kd=1
                        const float wk2 = wsc[18 + kh * 3 + kw];  // kd=2
#pragma unroll
                        for (int p = 0; p < 4; ++p) {
                            const float xv = row[kw + p];
                            // x[d] feeds d' = d - kd  ->  j = dd + 2 - kd
                            Aacc[dd + 2][p] = fmaf(xv, wk0, Aacc[dd + 2][p]);
                            Aacc[dd + 1][p] = fmaf(xv, wk1, Aacc[dd + 1][p]);
                            Aacc[dd + 0][p] = fmaf(xv, wk2, Aacc[dd + 0][p]);
                        }
                    }
                }
            }
        }

        // ---- min over completed outputs: j=0..7 <-> d' = c*8-2 .. c*8+5
        const bool full = (c > 0);  // c=0: j=0,1 are d'=-2,-1 (invalid)
#pragma unroll
        for (int j = 0; j < 8; ++j) {
            if (j >= 2 || full) {
#pragma unroll
                for (int p = 0; p < 4; ++p)
                    mv[p] = fminf(mv[p], Aacc[j][p]);
            }
        }
        // ---- carry j=8,9 -> j=0,1; zero the rest ----
#pragma unroll
        for (int p = 0; p < 4; ++p) {
            Aacc[0][p] = Aacc[8][p];
            Aacc[1][p] = Aacc[9][p];
        }
#pragma unroll
        for (int j = 2; j < 10; ++j)
#pragma unroll
            for (int p = 0; p < 4; ++p) Aacc[j][p] = 0.f;
    }

    // ---- epilogue: exchange via LDS, softmax over 16 channels ----
    const int px0 = r0 * 32 + wc;
#pragma unroll
    for (int pp = 0; pp < 4; ++pp)
        sm[(px0 + pp) * 17 + wv] = mv[pp] + bv;
    __syncthreads();

    const int hp = h0 + r0;
#pragma unroll
    for (int pp = 0; pp < 4; ++pp) {
        const int px = px0 + pp;
        float mx = -1e30f;
#pragma unroll
        for (int j = 0; j < 16; ++j) mx = fmaxf(mx, sm[px * 17 + j]);
        float sum = 0.f;
#pragma unroll
        for (int j = 0; j < 16; ++j) sum += __expf(sm[px * 17 + j] - mx);
        const int wp = w0 + wc + pp;
        if (hp < 62 && wp < 62) {
            const float e = __expf(sm[px * 17 + wv] - mx);
            out[(((size_t)n * 16 + wv) * 62 + hp) * 62 + wp] = e / sum;
        }
    }
}

extern "C" void kernel_launch(void* const* d_in, const int* in_sizes, int n_in,
                              void* d_out, int out_size, void* d_ws, size_t ws_size,
                              hipStream_t stream) {
    const float* x    = (const float*)d_in[0];
    const float* wgt  = (const float*)d_in[1];
    const float* bias = (const float*)d_in[2];
    float* out        = (float*)d_out;
    dim3 grid(2, 8, 16);   // (w-tiles, h-tiles, n)
    dim3 block(1024);      // 16 waves: one per output channel
    hipLaunchKernelGGL(conv3d_min_softmax, grid, block, 0, stream,
                       x, wgt, bias, out);
}

// Round 13
// 245.913 us; speedup vs baseline: 1.1017x; 1.1017x over previous
//
#include <hip/hip_runtime.h>
#include <math.h>

// Fused Conv3d(3->16, k=3, valid) + bias + min over D + softmax over C.
// N=16, CIN=3, COUT=16, K=3, D=H=W=64 -> out [16,16,62,62] fp32.
//
// R16: design-for-64-VGPR. R12/R14/R15 proved a 1024-thread block is
// PINNED to the 64-VGPR bin on this toolchain (default, waves_per_eu(4),
// launch_bounds(1024,1) all gave VGPR=64 + ~170MB spill of Aacc[10][4]).
// Stop fighting the allocator: halve chunk depth CH 8->4 so the acc bank
// is Aacc[6][4] = 24 regs; total footprint ~50 (R11 calibration: CH=8
// 2px Aacc[10][2]=20 -> VGPR=32, i.e. ~12 overhead). Fits 64, no spill,
// no attribute. Keeps the 4px LDS efficiency (b128+b64 per 36 FMAs ->
// ~70us/CU LDS vs R11's ~92us) at the same ~69us/SIMD FMA floor.
// Costs: 16 chunks/barriers instead of 8 (a few us), same FMA/DMA total.
// Structure: wave-per-channel (16 waves), SGPR weights via rolled ci,
// double-buffered global_load_lds, stride-17 LDS softmax exchange.
// Tile 8h x 32w, grid (2,8,16)=256 blocks, 16 waves/CU = 4 waves/SIMD.
// Tripwires: VGPR 45-60 + WRITE ~4.6MB = clean; VGPR=64 + WRITE huge
// => footprint model wrong, revert to R11.

#define CH 4  // d-slices per staged chunk (halved to fit 64 VGPRs)

__global__ __launch_bounds__(1024)
void conv3d_min_softmax(
    const float* __restrict__ x,     // [16,3,64,64,64]
    const float* __restrict__ wgt,   // [16,3,3,3,3]
    const float* __restrict__ bias,  // [16]
    float* __restrict__ out)         // [16,16,62,62]
{
    const int tid = threadIdx.x;
    // wave id == output channel; readfirstlane forces wave-uniform -> SGPR
    const int wv  = __builtin_amdgcn_readfirstlane(tid >> 6);
    const int l   = tid & 63;
    const int r0  = l >> 3;           // output row within tile (0..7)
    const int cg  = l & 7;            // col group (0..7)
    const int wc  = cg * 4;           // tile col of px0 (16B-aligned reads)
    const int n   = blockIdx.z;
    const int h0  = blockIdx.y * 8;   // 8 h-tiles cover rows 0..63 (62 valid)
    const int w0  = blockIdx.x * 32;  // 2 w-tiles cover cols 0..63 (62 valid)

    // staged x, double-buffered: [3 ci][CH dd][10 rows][36 cols] = 4320 f
    // = 1080 float4 slots (slot F <-> float index 4F, lane-linear for DMA).
    __shared__ __align__(16) float sx[2][4320];
    // softmax exchange: [256 px][17] (stride 17 -> conflict-free reads)
    __shared__ float sm[256 * 17];

    const float bv = bias[wv];

    // ---- hoisted staging address math (chunk 0) ----
    // slot F -> (ci, dd, rw, g):  F = ((ci*4+dd)*10 + rw)*9 + g
    int goff[2];  // global BYTE offsets; k=1 used only by tid<56
#pragma unroll
    for (int k = 0; k < 2; ++k) {
        int F = tid + 1024 * k;
        if (F > 1079) F = 1079;          // unused lanes: harmless dup
        int ci  = F / 360;               // 360 = 4*10*9
        int rem = F - ci * 360;
        int dd  = rem / 90;              // 90 = 10*9
        int rr  = rem - dd * 90;
        int rw  = rr / 9;
        int g   = rr - rw * 9;
        int gh  = h0 + rw;  if (gh > 63) gh = 63;   // clamp: halo, unused
        int gw  = w0 + g * 4; if (gw > 60) gw = 60; // clamp: cols>=62 unused
        goff[k] = (((ci * 64 + dd) * 64 + gh) * 64 + gw) * 4;
    }
    const char* xb = (const char*)(x + (size_t)n * 3 * 64 * 64 * 64);

    // accumulator bank: Aacc[j][px], j = d' - (c*4 - 2). j=0,1 carry
    // partials from the previous chunk; j=4,5 carry out. Static idx only.
    float Aacc[6][4];
#pragma unroll
    for (int j = 0; j < 6; ++j)
#pragma unroll
        for (int p = 0; p < 4; ++p) Aacc[j][p] = 0.f;
    float mv[4] = {1e30f, 1e30f, 1e30f, 1e30f};

    // ---- issue chunk 0 DMA (buffer 0) ----
    {
        char* lb = (char*)&sx[0][0];
        __builtin_amdgcn_global_load_lds(
            (const void*)(xb + goff[0]), (void*)(lb + tid * 16), 16, 0, 0);
        if (tid < 56)
            __builtin_amdgcn_global_load_lds(
                (const void*)(xb + goff[1]),
                (void*)(lb + (1024 + tid) * 16), 16, 0, 0);
    }

    for (int c = 0; c < 64 / CH; ++c) {
        // Drains vmcnt(0): chunk c's DMA landed; other buffer now free.
        __syncthreads();

        // ---- issue chunk c+1 DMA; flies during this chunk's compute ----
        if (c < 64 / CH - 1) {
            const char* xc = xb + (size_t)(c + 1) * (CH * 64 * 64 * 4);
            char* lb = (char*)&sx[(c + 1) & 1][0];
            __builtin_amdgcn_global_load_lds(
                (const void*)(xc + goff[0]), (void*)(lb + tid * 16),
                16, 0, 0);
            if (tid < 56)
                __builtin_amdgcn_global_load_lds(
                    (const void*)(xc + goff[1]),
                    (void*)(lb + (1024 + tid) * 16), 16, 0, 0);
        }

        const float* S = sx[c & 1];

        // ---- compute: ci ROLLED so only 27 weights live (SGPR-resident)
#pragma unroll 1
        for (int ci = 0; ci < 3; ++ci) {
            float wsc[27];  // wave-uniform -> s_load -> SGPRs
            {
                const float* wp_ = wgt + (wv * 3 + ci) * 27;
#pragma unroll
                for (int i = 0; i < 27; ++i) wsc[i] = wp_[i];
            }
            const float* Sci = S + ci * (CH * 10 * 36) + r0 * 36 + wc;
#pragma unroll
            for (int dd = 0; dd < CH; ++dd) {
#pragma unroll
                for (int kh = 0; kh < 3; ++kh) {
                    const float4 a = *(const float4*)&Sci[(dd * 10 + kh) * 36];
                    const float2 b =
                        *(const float2*)&Sci[(dd * 10 + kh) * 36 + 4];
                    const float row[6] = {a.x, a.y, a.z, a.w, b.x, b.y};
#pragma unroll
                    for (int kw = 0; kw < 3; ++kw) {
                        const float wk0 = wsc[0  + kh * 3 + kw];  // kd=0
                        const float wk1 = wsc[9  + kh * 3 + kw];  // kd=1
                        const float wk2 = wsc[18 + kh * 3 + kw];  // kd=2
#pragma unroll
                        for (int p = 0; p < 4; ++p) {
                            const float xv = row[kw + p];
                            // x[d] feeds d' = d - kd  ->  j = dd + 2 - kd
                            Aacc[dd + 2][p] = fmaf(xv, wk0, Aacc[dd + 2][p]);
                            Aacc[dd + 1][p] = fmaf(xv, wk1, Aacc[dd + 1][p]);
                            Aacc[dd + 0][p] = fmaf(xv, wk2, Aacc[dd + 0][p]);
                        }
                    }
                }
            }
        }

        // ---- min over completed outputs: j=0..3 <-> d' = c*4-2 .. c*4+1
        const bool full = (c > 0);  // c=0: j=0,1 are d'=-2,-1 (invalid)
#pragma unroll
        for (int j = 0; j < 4; ++j) {
            if (j >= 2 || full) {
#pragma unroll
                for (int p = 0; p < 4; ++p)
                    mv[p] = fminf(mv[p], Aacc[j][p]);
            }
        }
        // ---- carry j=4,5 -> j=0,1; zero the rest ----
#pragma unroll
        for (int p = 0; p < 4; ++p) {
            Aacc[0][p] = Aacc[4][p];
            Aacc[1][p] = Aacc[5][p];
        }
#pragma unroll
        for (int j = 2; j < 6; ++j)
#pragma unroll
            for (int p = 0; p < 4; ++p) Aacc[j][p] = 0.f;
    }

    // ---- epilogue: exchange via LDS, softmax over 16 channels ----
    const int px0 = r0 * 32 + wc;
#pragma unroll
    for (int pp = 0; pp < 4; ++pp)
        sm[(px0 + pp) * 17 + wv] = mv[pp] + bv;
    __syncthreads();

    const int hp = h0 + r0;
#pragma unroll
    for (int pp = 0; pp < 4; ++pp) {
        const int px = px0 + pp;
        float mx = -1e30f;
#pragma unroll
        for (int j = 0; j < 16; ++j) mx = fmaxf(mx, sm[px * 17 + j]);
        float sum = 0.f;
#pragma unroll
        for (int j = 0; j < 16; ++j) sum += __expf(sm[px * 17 + j] - mx);
        const int wp = w0 + wc + pp;
        if (hp < 62 && wp < 62) {
            const float e = __expf(sm[px * 17 + wv] - mx);
            out[(((size_t)n * 16 + wv) * 62 + hp) * 62 + wp] = e / sum;
        }
    }
}

extern "C" void kernel_launch(void* const* d_in, const int* in_sizes, int n_in,
                              void* d_out, int out_size, void* d_ws, size_t ws_size,
                              hipStream_t stream) {
    const float* x    = (const float*)d_in[0];
    const float* wgt  = (const float*)d_in[1];
    const float* bias = (const float*)d_in[2];
    float* out        = (float*)d_out;
    dim3 grid(2, 8, 16);   // (w-tiles, h-tiles, n)
    dim3 block(1024);      // 16 waves: one per output channel
    hipLaunchKernelGGL(conv3d_min_softmax, grid, block, 0, stream,
                       x, wgt, bias, out);
}